// Round 4
// baseline (4304.801 us; speedup 1.0000x reference)
//
#include <hip/hip_runtime.h>
#include <hip/hip_bf16.h>
#include <math.h>

// Problem constants
#define B_ 8
#define N_ 1025
#define C_ 3200
#define H_ 25
#define D_ 128
#define M_ (B_ * N_)       // 8200 rows
#define C3_ (3 * C_)       // 9600

typedef unsigned short u16;
typedef unsigned int u32;
typedef short bf16x8 __attribute__((ext_vector_type(8)));
typedef float f32x4 __attribute__((ext_vector_type(4)));

__device__ inline void load_lds16(const void* g, void* s) {
    __builtin_amdgcn_global_load_lds(
        (const __attribute__((address_space(1))) void*)g,
        (__attribute__((address_space(3))) void*)s, 16, 0, 0);
}

// Split two fp32 into packed bf16 hi + packed bf16 lo (x0 in low half).
__device__ inline void split_pair(float x0, float x1, u32& hpk, u32& lpk) {
    __hip_bfloat162 h2 = __float22bfloat162_rn(float2{x0, x1});
    union { __hip_bfloat162 b; u32 u; } cv; cv.b = h2;
    u32 h = cv.u;
    float hf0 = __uint_as_float(h << 16);
    float hf1 = __uint_as_float(h & 0xFFFF0000u);
    __hip_bfloat162 l2 = __float22bfloat162_rn(float2{x0 - hf0, x1 - hf1});
    union { __hip_bfloat162 b; u32 u; } cl; cl.b = l2;
    hpk = h; lpk = cl.u;
}

// Split one fp32 into bf16 hi + bf16 lo.
__device__ inline void split1(float x, u16& h, u16& l) {
    union { __hip_bfloat16 b; u16 u; } ch, cl;
    ch.b = __float2bfloat16(x);
    float hf = __uint_as_float(((u32)ch.u) << 16);
    cl.b = __float2bfloat16(x - hf);
    h = ch.u; l = cl.u;
}

// ---------------------------------------------------------------------------
// Transpose + split: in fp32 [K][strideN] (cols [0,Nn)) -> bf16 hi/lo [Nn][K]
// (k-contiguous). 32x32 tiles through LDS.
// ---------------------------------------------------------------------------
__global__ __launch_bounds__(256) void convert_tsplit(
    const float* __restrict__ in, u16* __restrict__ hi, u16* __restrict__ lo,
    int K, int Nn, int strideN)
{
    __shared__ float T[32][33];
    const int tid = threadIdx.x;
    const int nb = blockIdx.x * 32, kb = blockIdx.y * 32;
    #pragma unroll
    for (int p = 0; p < 4; ++p) {
        int k = p * 8 + (tid >> 5), n = tid & 31;
        T[k][n] = in[(size_t)(kb + k) * strideN + nb + n];
    }
    __syncthreads();
    const int nn = tid >> 3, k0 = (tid & 7) * 4;
    u32 h0, l0, h1, l1;
    split_pair(T[k0][nn], T[k0 + 1][nn], h0, l0);
    split_pair(T[k0 + 2][nn], T[k0 + 3][nn], h1, l1);
    size_t o = (size_t)(nb + nn) * K + kb + k0;
    *(uint2*)&hi[o] = make_uint2(h0, h1);
    *(uint2*)&lo[o] = make_uint2(l0, l1);
}

// ---------------------------------------------------------------------------
// GEMM variant 1: A fp32 [M][C_] (in-kernel split), B pre-split bf16 [N][C_].
// C[M,N](ldc) = A @ B^T + bias, 3-term split MFMA.
// 128x128 tile, BK=32, 4 waves (2x2). LDS layout [kc 4][row 128][8] so
// fragments are contiguous ds_read_b128. Next A-tile regs prefetched
// under the MFMAs. Bijective XCD swizzle.
// ---------------------------------------------------------------------------
__global__ __launch_bounds__(256) void gemm_asplit(
    const float* __restrict__ A,
    const u16* __restrict__ Bh, const u16* __restrict__ Bl,
    const float* __restrict__ bias, float* __restrict__ Cc,
    int M, int N, int ldc)
{
    __shared__ u16 As_h[4][128][8];
    __shared__ u16 As_l[4][128][8];
    __shared__ u16 Bs_h[4][128][8];
    __shared__ u16 Bs_l[4][128][8];

    const int tid  = threadIdx.x;
    const int lane = tid & 63;
    const int w    = tid >> 6;
    const int wm   = w & 1, wn = w >> 1;
    const int lr = lane & 15, lg = lane >> 4;

    const int gX   = gridDim.x;
    const int nwg  = gX * gridDim.y;
    const int orig = blockIdx.y * gX + blockIdx.x;
    const int q8 = nwg >> 3, r8 = nwg & 7;
    const int xcd = orig & 7, oi = orig >> 3;
    const int wg = (xcd < r8 ? xcd * (q8 + 1)
                             : r8 * (q8 + 1) + (xcd - r8) * q8) + oi;
    const int rowBase = (wg / gX) * 128;
    const int colBase = (wg % gX) * 128;

    // A staging: thread -> (row 0..127, k-half 0/16)
    const int arow = tid >> 1;
    const int akh  = (tid & 1) * 16;
    const int kc0  = akh >> 3;
    int gr0 = rowBase + arow; if (gr0 >= M) gr0 = M - 1;
    const float* aptr = A + (size_t)gr0 * C_ + akh;

    f32x4 acc[4][4] = {};

    float4 a0 = *(const float4*)(aptr + 0);
    float4 a1 = *(const float4*)(aptr + 4);
    float4 a2 = *(const float4*)(aptr + 8);
    float4 a3 = *(const float4*)(aptr + 12);

    for (int k0 = 0; k0 < C_; k0 += 32) {
        // ---- B tiles via 16B global->LDS DMA ----
        #pragma unroll
        for (int p = 0; p < 2; ++p) {
            int c = p * 256 + tid;
            int row = c & 127, kc = c >> 7;
            int ldsOff = (p * 256 + w * 64) * 8;          // wave-uniform base
            size_t boff = (size_t)(colBase + row) * C_ + k0 + kc * 8;
            load_lds16(Bh + boff, (u16*)Bs_h + ldsOff);
            load_lds16(Bl + boff, (u16*)Bs_l + ldsOff);
        }
        // ---- A: split current regs -> LDS (16B stores) ----
        u32 h0,h1,h2,h3,h4,h5,h6,h7, l0,l1,l2,l3,l4,l5,l6,l7;
        split_pair(a0.x, a0.y, h0, l0); split_pair(a0.z, a0.w, h1, l1);
        split_pair(a1.x, a1.y, h2, l2); split_pair(a1.z, a1.w, h3, l3);
        split_pair(a2.x, a2.y, h4, l4); split_pair(a2.z, a2.w, h5, l5);
        split_pair(a3.x, a3.y, h6, l6); split_pair(a3.z, a3.w, h7, l7);
        *(uint4*)&As_h[kc0][arow][0]     = make_uint4(h0, h1, h2, h3);
        *(uint4*)&As_h[kc0 + 1][arow][0] = make_uint4(h4, h5, h6, h7);
        *(uint4*)&As_l[kc0][arow][0]     = make_uint4(l0, l1, l2, l3);
        *(uint4*)&As_l[kc0 + 1][arow][0] = make_uint4(l4, l5, l6, l7);
        // ---- prefetch next A regs (in flight across MFMAs) ----
        if (k0 + 32 < C_) {
            const float* ap = aptr + k0 + 32;
            a0 = *(const float4*)(ap + 0);
            a1 = *(const float4*)(ap + 4);
            a2 = *(const float4*)(ap + 8);
            a3 = *(const float4*)(ap + 12);
        }
        __syncthreads();

        bf16x8 ah[4], al[4], bh[4], bl[4];
        #pragma unroll
        for (int i = 0; i < 4; ++i) {
            ah[i] = *(const bf16x8*)&As_h[lg][wm * 64 + i * 16 + lr][0];
            al[i] = *(const bf16x8*)&As_l[lg][wm * 64 + i * 16 + lr][0];
            bh[i] = *(const bf16x8*)&Bs_h[lg][wn * 64 + i * 16 + lr][0];
            bl[i] = *(const bf16x8*)&Bs_l[lg][wn * 64 + i * 16 + lr][0];
        }
        #pragma unroll
        for (int j = 0; j < 4; ++j)
            #pragma unroll
            for (int i = 0; i < 4; ++i)
                acc[i][j] = __builtin_amdgcn_mfma_f32_16x16x32_bf16(
                    ah[i], bh[j], acc[i][j], 0, 0, 0);
        #pragma unroll
        for (int j = 0; j < 4; ++j)
            #pragma unroll
            for (int i = 0; i < 4; ++i)
                acc[i][j] = __builtin_amdgcn_mfma_f32_16x16x32_bf16(
                    al[i], bh[j], acc[i][j], 0, 0, 0);
        #pragma unroll
        for (int j = 0; j < 4; ++j)
            #pragma unroll
            for (int i = 0; i < 4; ++i)
                acc[i][j] = __builtin_amdgcn_mfma_f32_16x16x32_bf16(
                    ah[i], bl[j], acc[i][j], 0, 0, 0);
        __syncthreads();
    }

    #pragma unroll
    for (int i = 0; i < 4; ++i) {
        #pragma unroll
        for (int j = 0; j < 4; ++j) {
            int gc = colBase + wn * 64 + j * 16 + lr;
            float bv = bias[gc];
            #pragma unroll
            for (int r = 0; r < 4; ++r) {
                int gr = rowBase + wm * 64 + i * 16 + lg * 4 + r;
                if (gr < M) Cc[(size_t)gr * ldc + gc] = acc[i][j][r] + bv;
            }
        }
    }
}

// ---------------------------------------------------------------------------
// GEMM variant 2: both operands pre-split bf16 (A [M][C_], B [N][C_]).
// Pure global_load_lds staging, zero in-loop VALU conversion.
// ---------------------------------------------------------------------------
__global__ __launch_bounds__(256) void gemm_bf16split(
    const u16* __restrict__ Ah, const u16* __restrict__ Al,
    const u16* __restrict__ Bh, const u16* __restrict__ Bl,
    const float* __restrict__ bias, float* __restrict__ Cc,
    int M, int N, int ldc)
{
    __shared__ u16 As_h[4][128][8];
    __shared__ u16 As_l[4][128][8];
    __shared__ u16 Bs_h[4][128][8];
    __shared__ u16 Bs_l[4][128][8];

    const int tid  = threadIdx.x;
    const int lane = tid & 63;
    const int w    = tid >> 6;
    const int wm   = w & 1, wn = w >> 1;
    const int lr = lane & 15, lg = lane >> 4;

    const int gX   = gridDim.x;
    const int nwg  = gX * gridDim.y;
    const int orig = blockIdx.y * gX + blockIdx.x;
    const int q8 = nwg >> 3, r8 = nwg & 7;
    const int xcd = orig & 7, oi = orig >> 3;
    const int wg = (xcd < r8 ? xcd * (q8 + 1)
                             : r8 * (q8 + 1) + (xcd - r8) * q8) + oi;
    const int rowBase = (wg / gX) * 128;
    const int colBase = (wg % gX) * 128;

    f32x4 acc[4][4] = {};

    for (int k0 = 0; k0 < C_; k0 += 32) {
        #pragma unroll
        for (int p = 0; p < 2; ++p) {
            int c = p * 256 + tid;
            int row = c & 127, kc = c >> 7;
            int ldsOff = (p * 256 + w * 64) * 8;
            int ar = rowBase + row; if (ar >= M) ar = M - 1;
            size_t aoff = (size_t)ar * C_ + k0 + kc * 8;
            size_t boff = (size_t)(colBase + row) * C_ + k0 + kc * 8;
            load_lds16(Ah + aoff, (u16*)As_h + ldsOff);
            load_lds16(Al + aoff, (u16*)As_l + ldsOff);
            load_lds16(Bh + boff, (u16*)Bs_h + ldsOff);
            load_lds16(Bl + boff, (u16*)Bs_l + ldsOff);
        }
        __syncthreads();

        bf16x8 ah[4], al[4], bh[4], bl[4];
        #pragma unroll
        for (int i = 0; i < 4; ++i) {
            ah[i] = *(const bf16x8*)&As_h[lg][wm * 64 + i * 16 + lr][0];
            al[i] = *(const bf16x8*)&As_l[lg][wm * 64 + i * 16 + lr][0];
            bh[i] = *(const bf16x8*)&Bs_h[lg][wn * 64 + i * 16 + lr][0];
            bl[i] = *(const bf16x8*)&Bs_l[lg][wn * 64 + i * 16 + lr][0];
        }
        #pragma unroll
        for (int j = 0; j < 4; ++j)
            #pragma unroll
            for (int i = 0; i < 4; ++i)
                acc[i][j] = __builtin_amdgcn_mfma_f32_16x16x32_bf16(
                    ah[i], bh[j], acc[i][j], 0, 0, 0);
        #pragma unroll
        for (int j = 0; j < 4; ++j)
            #pragma unroll
            for (int i = 0; i < 4; ++i)
                acc[i][j] = __builtin_amdgcn_mfma_f32_16x16x32_bf16(
                    al[i], bh[j], acc[i][j], 0, 0, 0);
        #pragma unroll
        for (int j = 0; j < 4; ++j)
            #pragma unroll
            for (int i = 0; i < 4; ++i)
                acc[i][j] = __builtin_amdgcn_mfma_f32_16x16x32_bf16(
                    ah[i], bl[j], acc[i][j], 0, 0, 0);
        __syncthreads();
    }

    #pragma unroll
    for (int i = 0; i < 4; ++i) {
        #pragma unroll
        for (int j = 0; j < 4; ++j) {
            int gc = colBase + wn * 64 + j * 16 + lr;
            float bv = bias[gc];
            #pragma unroll
            for (int r = 0; r < 4; ++r) {
                int gr = rowBase + wm * 64 + i * 16 + lg * 4 + r;
                if (gr < M) Cc[(size_t)gr * ldc + gc] = acc[i][j][r] + bv;
            }
        }
    }
}

// ---------------------------------------------------------------------------
// RMSNorm over full C=3200 for q and k slices (float4 vectorized).
// ---------------------------------------------------------------------------
__global__ __launch_bounds__(256) void rmsnorm_kernel(
    float* __restrict__ qkv, const float* __restrict__ qw,
    const float* __restrict__ kw)
{
    const int row   = blockIdx.x >> 1;
    const int which = blockIdx.x & 1;
    float* p = qkv + (size_t)row * C3_ + which * C_;
    const float* w = which ? kw : qw;
    const int tid = threadIdx.x;

    float ss = 0.f;
    for (int i = tid; i < C_ / 4; i += 256) {
        float4 v = ((const float4*)p)[i];
        ss += v.x * v.x + v.y * v.y + v.z * v.z + v.w * v.w;
    }
    #pragma unroll
    for (int off = 32; off; off >>= 1) ss += __shfl_down(ss, off);

    __shared__ float wsum[4];
    __shared__ float stot;
    if ((tid & 63) == 0) wsum[tid >> 6] = ss;
    __syncthreads();
    if (tid == 0) stot = wsum[0] + wsum[1] + wsum[2] + wsum[3];
    __syncthreads();

    const float scale = rsqrtf(stot / (float)C_ + 1e-6f);
    for (int i = tid; i < C_ / 4; i += 256) {
        float4 v  = ((const float4*)p)[i];
        float4 wv = ((const float4*)w)[i];
        v.x *= scale * wv.x; v.y *= scale * wv.y;
        v.z *= scale * wv.z; v.w *= scale * wv.w;
        ((float4*)p)[i] = v;
    }
}

// ---------------------------------------------------------------------------
// Flash attention via split-bf16 MFMA. Writes attn output directly as
// bf16 hi/lo split arrays (consumed by gemm_bf16split).
// ---------------------------------------------------------------------------
__global__ __launch_bounds__(256, 2) void flash_mfma(
    const float* __restrict__ qkv, u16* __restrict__ aoh, u16* __restrict__ aol)
{
    __shared__ u16 Kh[4][32][32];
    __shared__ u16 Kl[4][32][32];
    __shared__ u16 Vth[128][40];
    __shared__ u16 Vtl[128][40];
    __shared__ u16 Ph[4][16][40];
    __shared__ u16 Pl[4][16][40];

    const int b   = blockIdx.z;
    const int h   = blockIdx.y;
    const int q0  = blockIdx.x * 64;
    const int tid = threadIdx.x;
    const int lane = tid & 63;
    const int w    = tid >> 6;
    const int lr = lane & 15, lg = lane >> 4;
    const float scale = 0.088388347648318447f;

    bf16x8 qh[4], ql[4];
    {
        int qr = q0 + w * 16 + lr;
        if (qr >= N_) qr = N_ - 1;
        const float* qp = qkv + (size_t)(b * N_ + qr) * C3_ + h * D_;
        #pragma unroll
        for (int c = 0; c < 4; ++c) {
            float4 x0 = *(const float4*)(qp + c * 32 + lg * 8);
            float4 x1 = *(const float4*)(qp + c * 32 + lg * 8 + 4);
            union { u32 u[4]; bf16x8 v; } Hq, Lq;
            split_pair(x0.x * scale, x0.y * scale, Hq.u[0], Lq.u[0]);
            split_pair(x0.z * scale, x0.w * scale, Hq.u[1], Lq.u[1]);
            split_pair(x1.x * scale, x1.y * scale, Hq.u[2], Lq.u[2]);
            split_pair(x1.z * scale, x1.w * scale, Hq.u[3], Lq.u[3]);
            qh[c] = Hq.v; ql[c] = Lq.v;
        }
    }

    const float* Kbase = qkv + (size_t)b * N_ * C3_ + C_ + h * D_;
    const float* Vbase = qkv + (size_t)b * N_ * C3_ + 2 * C_ + h * D_;

    const int skr = tid >> 3;
    const int skd = (tid & 7) * 16;
    const int svk = (tid & 15) * 2;
    const int svd = (tid >> 4) * 4;

    float4 kg[4], vg[2][2];

    auto stage_load = [&](int kt) {
        int kk = kt * 32 + skr;
        if (kk < N_) {
            const float* p = Kbase + (size_t)kk * C3_ + skd;
            kg[0] = *(const float4*)(p + 0);
            kg[1] = *(const float4*)(p + 4);
            kg[2] = *(const float4*)(p + 8);
            kg[3] = *(const float4*)(p + 12);
        } else {
            kg[0] = kg[1] = kg[2] = kg[3] = make_float4(0.f, 0.f, 0.f, 0.f);
        }
        #pragma unroll
        for (int r = 0; r < 2; ++r) {
            int vk = kt * 32 + svk + r;
            if (vk < N_) {
                const float* p = Vbase + (size_t)vk * C3_ + svd;
                vg[0][r] = *(const float4*)(p);
                vg[1][r] = *(const float4*)(p + 64);
            } else {
                vg[0][r] = make_float4(0.f, 0.f, 0.f, 0.f);
                vg[1][r] = make_float4(0.f, 0.f, 0.f, 0.f);
            }
        }
    };

    auto stage_store = [&]() {
        #pragma unroll
        for (int i = 0; i < 4; ++i) {
            int d = skd + i * 4;
            int c = d >> 5, dd = d & 31;
            u32 h0, l0, h1, l1;
            split_pair(kg[i].x, kg[i].y, h0, l0);
            split_pair(kg[i].z, kg[i].w, h1, l1);
            *(uint2*)&Kh[c][skr][dd] = make_uint2(h0, h1);
            *(uint2*)&Kl[c][skr][dd] = make_uint2(l0, l1);
        }
        #pragma unroll
        for (int half = 0; half < 2; ++half) {
            float a0[4] = { vg[half][0].x, vg[half][0].y, vg[half][0].z, vg[half][0].w };
            float a1[4] = { vg[half][1].x, vg[half][1].y, vg[half][1].z, vg[half][1].w };
            #pragma unroll
            for (int i = 0; i < 4; ++i) {
                int d = svd + half * 64 + i;
                u32 hp, lp;
                split_pair(a0[i], a1[i], hp, lp);
                *(u32*)&Vth[d][svk] = hp;
                *(u32*)&Vtl[d][svk] = lp;
            }
        }
    };

    f32x4 oacc[8] = {};
    float m[4]    = { -INFINITY, -INFINITY, -INFINITY, -INFINITY };
    float lsum[4] = { 0.f, 0.f, 0.f, 0.f };

    const int nkt = (N_ + 31) / 32;
    stage_load(0);
    for (int kt = 0; kt < nkt; ++kt) {
        __syncthreads();
        stage_store();
        __syncthreads();
        if (kt + 1 < nkt) stage_load(kt + 1);

        f32x4 s0 = {}, s1 = {};
        #pragma unroll
        for (int c = 0; c < 4; ++c) {
            bf16x8 kh0 = *(const bf16x8*)&Kh[c][lr][lg * 8];
            bf16x8 kl0 = *(const bf16x8*)&Kl[c][lr][lg * 8];
            bf16x8 kh1 = *(const bf16x8*)&Kh[c][16 + lr][lg * 8];
            bf16x8 kl1 = *(const bf16x8*)&Kl[c][16 + lr][lg * 8];
            s0 = __builtin_amdgcn_mfma_f32_16x16x32_bf16(qh[c], kh0, s0, 0, 0, 0);
            s0 = __builtin_amdgcn_mfma_f32_16x16x32_bf16(ql[c], kh0, s0, 0, 0, 0);
            s0 = __builtin_amdgcn_mfma_f32_16x16x32_bf16(qh[c], kl0, s0, 0, 0, 0);
            s1 = __builtin_amdgcn_mfma_f32_16x16x32_bf16(qh[c], kh1, s1, 0, 0, 0);
            s1 = __builtin_amdgcn_mfma_f32_16x16x32_bf16(ql[c], kh1, s1, 0, 0, 0);
            s1 = __builtin_amdgcn_mfma_f32_16x16x32_bf16(qh[c], kl1, s1, 0, 0, 0);
        }

        const int kb = kt * 32;
        const bool v0 = (kb + lr) < N_;
        const bool v1 = (kb + 16 + lr) < N_;
        #pragma unroll
        for (int r = 0; r < 4; ++r) {
            if (!v0) s0[r] = -INFINITY;
            if (!v1) s1[r] = -INFINITY;
        }

        #pragma unroll
        for (int r = 0; r < 4; ++r) {
            float mt = fmaxf(s0[r], s1[r]);
            mt = fmaxf(mt, __shfl_xor(mt, 1));
            mt = fmaxf(mt, __shfl_xor(mt, 2));
            mt = fmaxf(mt, __shfl_xor(mt, 4));
            mt = fmaxf(mt, __shfl_xor(mt, 8));
            float mn = fmaxf(m[r], mt);
            float al = __expf(m[r] - mn);
            m[r] = mn;
            float p0 = __expf(s0[r] - mn);
            float p1 = __expf(s1[r] - mn);
            float ls = p0 + p1;
            ls += __shfl_xor(ls, 1);
            ls += __shfl_xor(ls, 2);
            ls += __shfl_xor(ls, 4);
            ls += __shfl_xor(ls, 8);
            lsum[r] = lsum[r] * al + ls;
            #pragma unroll
            for (int dt = 0; dt < 8; ++dt) oacc[dt][r] *= al;

            u16 hh, ll;
            split1(p0, hh, ll);
            Ph[w][lg * 4 + r][lr] = hh;
            Pl[w][lg * 4 + r][lr] = ll;
            split1(p1, hh, ll);
            Ph[w][lg * 4 + r][16 + lr] = hh;
            Pl[w][lg * 4 + r][16 + lr] = ll;
        }

        bf16x8 pah = *(const bf16x8*)&Ph[w][lr][lg * 8];
        bf16x8 pal = *(const bf16x8*)&Pl[w][lr][lg * 8];
        #pragma unroll
        for (int dt = 0; dt < 8; ++dt) {
            bf16x8 vh = *(const bf16x8*)&Vth[dt * 16 + lr][lg * 8];
            bf16x8 vl = *(const bf16x8*)&Vtl[dt * 16 + lr][lg * 8];
            oacc[dt] = __builtin_amdgcn_mfma_f32_16x16x32_bf16(pah, vh, oacc[dt], 0, 0, 0);
            oacc[dt] = __builtin_amdgcn_mfma_f32_16x16x32_bf16(pal, vh, oacc[dt], 0, 0, 0);
            oacc[dt] = __builtin_amdgcn_mfma_f32_16x16x32_bf16(pah, vl, oacc[dt], 0, 0, 0);
        }
    }

    // epilogue: write bf16 hi/lo splits of the normalized output
    #pragma unroll
    for (int r = 0; r < 4; ++r) {
        int q = q0 + w * 16 + lg * 4 + r;
        if (q < N_) {
            float inv = 1.f / lsum[r];
            size_t base = (size_t)(b * N_ + q) * C_ + h * D_ + lr;
            #pragma unroll
            for (int dt = 0; dt < 8; ++dt) {
                u16 hh, ll;
                split1(oacc[dt][r] * inv, hh, ll);
                aoh[base + dt * 16] = hh;
                aol[base + dt * 16] = ll;
            }
        }
    }
}

// ---------------------------------------------------------------------------
// Workspace plan (peak 419.84 MB — identical to the proven footprint):
//   [0, fQ*4)           qkv fp32 (Phase A out, B in)   / proj_w splits (C)
//   [fQ*4, +fA*4)       region R: w-chunk splits (A)   / attn splits (B,C)
// ---------------------------------------------------------------------------
extern "C" void kernel_launch(void* const* d_in, const int* in_sizes, int n_in,
                              void* d_out, int out_size, void* d_ws, size_t ws_size,
                              hipStream_t stream)
{
    const float* x        = (const float*)d_in[0];
    const float* qkv_w    = (const float*)d_in[1];
    const float* qkv_b    = (const float*)d_in[2];
    const float* q_norm_w = (const float*)d_in[3];
    const float* k_norm_w = (const float*)d_in[4];
    const float* proj_w   = (const float*)d_in[5];
    const float* proj_b   = (const float*)d_in[6];
    float* out = (float*)d_out;

    const size_t fQ = (size_t)M_ * C3_;    // qkv floats
    const size_t fA = (size_t)M_ * C_;     // attn floats
    const size_t wC = (size_t)C_ * C_;     // one weight chunk elems

    float* qkv = (float*)d_ws;
    u16*   R   = (u16*)(qkv + fQ);         // fA*4 bytes available

    dim3 blk(256);

    // ---- Phase A: QKV GEMM as 3 sub-GEMMs (q, k, v) ----
    u16* wh = R;
    u16* wl = wh + wC;
    for (int j = 0; j < 3; ++j) {
        convert_tsplit<<<dim3(C_ / 32, C_ / 32), blk, 0, stream>>>(
            qkv_w + (size_t)j * C_, wh, wl, C_, C_, C3_);
        gemm_asplit<<<dim3(C_ / 128, (M_ + 127) / 128), blk, 0, stream>>>(
            x, wh, wl, qkv_b + j * C_, qkv + (size_t)j * C_, M_, C_, C3_);
    }

    // ---- Phase B: RMSNorm + flash attention (writes attn splits into R) ----
    rmsnorm_kernel<<<dim3(M_ * 2), blk, 0, stream>>>(qkv, q_norm_w, k_norm_w);
    u16* aoh = R;
    u16* aol = R + fA;
    flash_mfma<<<dim3((N_ + 63) / 64, H_, B_), blk, 0, stream>>>(qkv, aoh, aol);

    // ---- Phase C: output projection (qkv region now free) ----
    u16* ph = (u16*)d_ws;
    u16* pl = ph + wC;
    convert_tsplit<<<dim3(C_ / 32, C_ / 32), blk, 0, stream>>>(
        proj_w, ph, pl, C_, C_, C_);
    gemm_bf16split<<<dim3(C_ / 128, (M_ + 127) / 128), blk, 0, stream>>>(
        aoh, aol, ph, pl, proj_b, out, M_, C_, C_);
}